// Round 4
// baseline (558.538 us; speedup 1.0000x reference)
//
#include <hip/hip_runtime.h>
#include <cstdint>
#include <cstddef>

// SwitchingRNN: B=64, T=512, I=256, L=512, K=8.  Output dtype: FLOAT32.
//
// R4 == R3 resubmitted (R3 bench died with "container failed twice" -- infra
// failure, no counters; source audit found no deadlock/OOB/LDS-overflow).
// R3 rationale:
//   - R2's W-residency silently failed: VGPR_Count stayed 128, wreg spilled,
//     every step re-loaded ~40 frags from scratch (MfmaUtil 3.3%).
//   - amdgpu_waves_per_eu(2,2) pins 2 waves/SIMD -> 256-VGPR budget.
//   - W split: kt0..7 in VGPRs (128 regs), kt8..11 in LDS (128 KB),
//     kt12..15 streamed from L2 (128 KB/step), two halves fenced by
//     sched_barrier to cap live range. Peak live ~230 < 256 -> no spills.
//   - X folded into the MFMA C-operand (acc init = X): -16 regs.
//   - xgemm rewritten with MFMA (verified fragment mappings), be folded.

typedef _Float16 f16;
typedef _Float16 h2v __attribute__((ext_vector_type(2)));
typedef _Float16 f16x8 __attribute__((ext_vector_type(8)));
typedef float f32x4 __attribute__((ext_vector_type(4)));

#if defined(__has_builtin)
#if __has_builtin(__builtin_amdgcn_sched_barrier)
#define SCHED_FENCE() __builtin_amdgcn_sched_barrier(0)
#endif
#endif
#ifndef SCHED_FENCE
#define SCHED_FENCE()
#endif

#if defined(__has_attribute)
#if __has_attribute(amdgpu_waves_per_eu)
#define WAVES22 __attribute__((amdgpu_waves_per_eu(2, 2)))
#endif
#endif
#ifndef WAVES22
#define WAVES22
#endif

// ---- WhhEff[b][l][j] = sum_k p[b,k] * W_hh[k*512+l][j]  (f16 out)
__global__ __launch_bounds__(512) void mix_whh_kernel(
    const float* __restrict__ Whh, const float* __restrict__ p, f16* __restrict__ out) {
  __shared__ float ps[512];
  const int l = blockIdx.x, j = threadIdx.x;
  ps[j] = p[j];
  __syncthreads();
  float w[8];
#pragma unroll
  for (int k = 0; k < 8; ++k) w[k] = Whh[(size_t)(k * 512 + l) * 512 + j];
#pragma unroll 4
  for (int b = 0; b < 64; ++b) {
    float s = 0.f;
#pragma unroll
    for (int k = 0; k < 8; ++k) s += ps[b * 8 + k] * w[k];
    out[((size_t)(b * 512) + l) * 512 + j] = (f16)s;
  }
}

// ---- WihEff[b][l][j] = sum_k p[b,k] * W_ih[k*512+l][j]  (f16 out), j<256
__global__ __launch_bounds__(256) void mix_wih_kernel(
    const float* __restrict__ Wih, const float* __restrict__ p, f16* __restrict__ out) {
  __shared__ float ps[512];
  const int l = blockIdx.x, j = threadIdx.x;
  ps[j] = p[j];
  ps[j + 256] = p[j + 256];
  __syncthreads();
  float w[8];
#pragma unroll
  for (int k = 0; k < 8; ++k) w[k] = Wih[(size_t)(k * 512 + l) * 256 + j];
#pragma unroll 4
  for (int b = 0; b < 64; ++b) {
    float s = 0.f;
#pragma unroll
    for (int k = 0; k < 8; ++k) s += ps[b * 8 + k] * w[k];
    out[((size_t)(b * 512) + l) * 256 + j] = (f16)s;
  }
}

// ---- beff[b][l] = sum_k p[b,k]*(b_ih+b_hh+bias)[k*512+l]  (f32)
__global__ __launch_bounds__(512) void beff_kernel(
    const float* __restrict__ p, const float* __restrict__ b_ih,
    const float* __restrict__ b_hh, const float* __restrict__ bias,
    float* __restrict__ beff) {
  const int b = blockIdx.x, l = threadIdx.x;
  float s = 0.f;
#pragma unroll
  for (int k = 0; k < 8; ++k) {
    int o = k * 512 + l;
    s += p[b * 8 + k] * (b_ih[o] + b_hh[o] + bias[o]);
  }
  beff[b * 512 + l] = s;
}

// ---- X[b][t][l] = inp[b,t,:] . WihE[b,l,:] + beff[b][l]  -> f32 into d_out.
// MFMA version. Block = 256 thr (4 waves), tile 64t x 64l, K=256 (8 kt).
// Verified mappings (chunk_kernel / m89): A-frag lane: Mrow=lane&15,
// k=kt*32+(lane>>4)*8+e. B-frag lane: Nrow=nt*16+(lane&15), same k.
// D: acc[nt][r] -> Mrow=(lane>>4)*4+r, Ncol=(lane&15).
__global__ __launch_bounds__(256) void xgemm_kernel(
    const float* __restrict__ inp, const f16* __restrict__ Wih,
    const float* __restrict__ be, float* __restrict__ X) {
  // B tile in LDS as 16B granules: g = (kt*4+nt)*64 + lg*16 + lr
  __shared__ __align__(16) char bsm[32768];
  const int tid = threadIdx.x;
  const int t0 = blockIdx.x * 64, l0 = blockIdx.y * 64, b = blockIdx.z;
  const int lane = tid & 63, w = tid >> 6;
  const int lr = lane & 15, lg = lane >> 4;

  // stage B: thread covers row = tid&63, kpart = tid>>6 (128 B of the row)
  {
    const int row = tid & 63, kp = tid >> 6;
    const char* src = (const char*)(Wih + ((size_t)(b * 512) + l0 + row) * 256) + kp * 128;
    const int nt_ = row >> 4, lr_ = row & 15;
#pragma unroll
    for (int ci = 0; ci < 8; ++ci) {
      const int kt = kp * 2 + (ci >> 2), lg_ = ci & 3;
      uint4 v = *(const uint4*)(src + ci * 16);
      *(uint4*)(bsm + (((kt * 4 + nt_) * 64 + lg_ * 16 + lr_) << 4)) = v;
    }
  }

  // A rows direct from global (no reuse across waves): row = t0+w*16+lr
  const float* arow = inp + ((size_t)(b * 512) + t0 + w * 16 + lr) * 256 + lg * 8;

  f32x4 acc[4];
#pragma unroll
  for (int nt = 0; nt < 4; ++nt)
#pragma unroll
    for (int q = 0; q < 4; ++q) acc[nt][q] = 0.f;

  __syncthreads();

#pragma unroll
  for (int kt = 0; kt < 8; ++kt) {
    float4 a0 = *(const float4*)(arow + kt * 32);
    float4 a1 = *(const float4*)(arow + kt * 32 + 4);
    f16x8 a;
    a[0] = (f16)a0.x; a[1] = (f16)a0.y; a[2] = (f16)a0.z; a[3] = (f16)a0.w;
    a[4] = (f16)a1.x; a[5] = (f16)a1.y; a[6] = (f16)a1.z; a[7] = (f16)a1.w;
#pragma unroll
    for (int nt = 0; nt < 4; ++nt) {
      f16x8 bv = *(const f16x8*)(bsm + (((kt * 4 + nt) * 64 + lg * 16 + lr) << 4));
      acc[nt] = __builtin_amdgcn_mfma_f32_16x16x32_f16(a, bv, acc[nt], 0, 0, 0);
    }
  }

  // D: t = t0 + w*16 + lg*4 + r ; l = l0 + nt*16 + lr
  float* xb = X + ((size_t)(b * 512) + t0 + w * 16 + lg * 4) * 512 + l0;
  const float* beb = be + b * 512 + l0;
#pragma unroll
  for (int r = 0; r < 4; ++r)
#pragma unroll
    for (int nt = 0; nt < 4; ++nt)
      xb[r * 512 + nt * 16 + lr] = acc[nt][r] + beb[nt * 16 + lr];
}

// ---- chunked scan, W-resident (fixed): 64 blocks (1/batch) x 512 thr.
// Per step: D[j][hrow] = sum_k Ht[k][j]*W[hrow][k] + X  (X as MFMA C-input).
// Column j consumes c_t with t = 32j - P + i at step i; keeps i>=P.
#define S_CHUNK 32
#define P_WARM 24
#define NSTEP (S_CHUNK + P_WARM)  // 56

__global__ __launch_bounds__(512) WAVES22
void chunk_kernel(const f16* Whh, const float* __restrict__ h0, float* out) {
  __shared__ f16x8 wlds[16 * 512];          // 131072 B: W kt8..11, all nt
  __shared__ __align__(16) char ht[16384];  // Ht[j][k] f16, XOR-swz

  const int tid = threadIdx.x;
  const int b = blockIdx.x;
  const int lane = tid & 63;
  const int w = tid >> 6;    // wave -> output rows [w*64, w*64+64)
  const int lr = lane & 15;  // A: j ; B/D: hrow%16
  const int lg = lane >> 4;  // k-group ; D: j-group

  // W frag (kt,nt) byte address: wbase + nt*16384 + kt*64
  const char* wbase =
      (const char*)(Whh + ((size_t)(b * 512) + w * 64 + lr) * 512) + lg * 16;

  // resident W, kt 0..7 -> VGPRs (128 regs)
  f16x8 wreg[8][4];
#pragma unroll
  for (int kt = 0; kt < 8; ++kt)
#pragma unroll
    for (int nt = 0; nt < 4; ++nt)
      wreg[kt][nt] = *(const f16x8*)(wbase + nt * 16384 + kt * 64);

  // resident W, kt 8..11 -> LDS, class c = (kt-8)*4 + nt
#pragma unroll
  for (int c = 0; c < 16; ++c) {
    const int kt = 8 + (c >> 2), nt = c & 3;
    wlds[c * 512 + tid] = *(const f16x8*)(wbase + nt * 16384 + kt * 64);
  }

  // Ht init: col 0 = h0 (persists through warm-up: writes skipped), rest 0
#pragma unroll
  for (int r = 0; r < 4; ++r) {
    const int j = lg * 4 + r;
#pragma unroll
    for (int nt = 0; nt < 4; ++nt) {
      const int k = w * 64 + nt * 16 + lr;
      const int off = (j * 1024 + k * 2) ^ ((j & 7) << 4);
      *(f16*)(ht + off) = (j == 0) ? (f16)h0[b * 512 + k] : (f16)0.f;
    }
  }

  // X/out pointer: column j = lg*4 + r lives at po0 + r*16384 + nt*16
  float* po0 = out + ((size_t)b * 262144) + w * 64 + lr +
               (ptrdiff_t)(128 * lg - P_WARM) * 512;

  __syncthreads();

#pragma unroll 1
  for (int i = 0; i < NSTEP; ++i) {
    const bool warm = (i < P_WARM);

    // acc init = X for this step (MFMA C-operand). Masked for t<0 (col 0
    // during warm-up). Stores to out (may alias Whh: no __restrict) keep
    // all in-loop W loads un-hoistable -> truly streamed.
    f32x4 acc[4];
#pragma unroll
    for (int nt = 0; nt < 4; ++nt)
#pragma unroll
      for (int r = 0; r < 4; ++r) {
        const bool valid = !(warm && (lg == 0) && (r == 0));
        acc[nt][r] = valid ? po0[r * 16384 + nt * 16] : 0.f;
      }

    // streamed W first half: kt 12,13
    f16x8 gwA[8];
#pragma unroll
    for (int g = 0; g < 8; ++g)
      gwA[g] = *(const f16x8*)(wbase + (g & 3) * 16384 + (12 + (g >> 2)) * 64);

    // MFMA kt 0..3 (wreg)
#pragma unroll
    for (int kt = 0; kt < 4; ++kt) {
      const int aoff = (lr * 1024 + kt * 64 + lg * 16) ^ ((lr & 7) << 4);
      const f16x8 a = *(const f16x8*)(ht + aoff);
#pragma unroll
      for (int nt = 0; nt < 4; ++nt)
        acc[nt] = __builtin_amdgcn_mfma_f32_16x16x32_f16(a, wreg[kt][nt], acc[nt], 0, 0, 0);
    }
    SCHED_FENCE();

    // streamed W second half: kt 14,15
    f16x8 gwB[8];
#pragma unroll
    for (int g = 0; g < 8; ++g)
      gwB[g] = *(const f16x8*)(wbase + (g & 3) * 16384 + (14 + (g >> 2)) * 64);

    // MFMA kt 4..7 (wreg)
#pragma unroll
    for (int kt = 4; kt < 8; ++kt) {
      const int aoff = (lr * 1024 + kt * 64 + lg * 16) ^ ((lr & 7) << 4);
      const f16x8 a = *(const f16x8*)(ht + aoff);
#pragma unroll
      for (int nt = 0; nt < 4; ++nt)
        acc[nt] = __builtin_amdgcn_mfma_f32_16x16x32_f16(a, wreg[kt][nt], acc[nt], 0, 0, 0);
    }
    SCHED_FENCE();

    // MFMA kt 8..11 (LDS W)
#pragma unroll
    for (int kt = 8; kt < 12; ++kt) {
      const int aoff = (lr * 1024 + kt * 64 + lg * 16) ^ ((lr & 7) << 4);
      const f16x8 a = *(const f16x8*)(ht + aoff);
#pragma unroll
      for (int nt = 0; nt < 4; ++nt)
        acc[nt] = __builtin_amdgcn_mfma_f32_16x16x32_f16(
            a, wlds[((kt - 8) * 4 + nt) * 512 + tid], acc[nt], 0, 0, 0);
    }

    // MFMA kt 12..15 (streamed W)
#pragma unroll
    for (int kt = 12; kt < 16; ++kt) {
      const int aoff = (lr * 1024 + kt * 64 + lg * 16) ^ ((lr & 7) << 4);
      const f16x8 a = *(const f16x8*)(ht + aoff);
#pragma unroll
      for (int nt = 0; nt < 4; ++nt) {
        const f16x8 bv = (kt < 14) ? gwA[(kt - 12) * 4 + nt] : gwB[(kt - 14) * 4 + nt];
        acc[nt] = __builtin_amdgcn_mfma_f32_16x16x32_f16(a, bv, acc[nt], 0, 0, 0);
      }
    }

    __syncthreads();  // all Ht reads complete before overwrite

    // epilogue: val = acc (already includes X); store states (i>=P);
    // write f16 state to Ht. Warm-up col 0's Ht write SKIPPED (stays h0).
#pragma unroll
    for (int r = 0; r < 4; ++r) {
      const int j = lg * 4 + r;
#pragma unroll
      for (int nt = 0; nt < 4; ++nt) {
        const float val = acc[nt][r];
        if (!warm) po0[r * 16384 + nt * 16] = val;  // states[t], t = 32j-P+i
        if (!(warm && j == 0)) {
          const int k = w * 64 + nt * 16 + lr;
          const int off = (j * 1024 + k * 2) ^ ((j & 7) << 4);
          *(f16*)(ht + off) = (f16)val;
        }
      }
    }
    // final hidden = states[511]: column 15 (lg==3, r==3) at the last step
    if (i == NSTEP - 1 && lg == 3) {
#pragma unroll
      for (int nt = 0; nt < 4; ++nt)
        out[16777216 + b * 512 + w * 64 + nt * 16 + lr] = acc[nt][3];
    }
    po0 += 512;
    __syncthreads();
  }
}

extern "C" void kernel_launch(void* const* d_in, const int* in_sizes, int n_in,
                              void* d_out, int out_size, void* d_ws, size_t ws_size,
                              hipStream_t stream) {
  (void)in_sizes; (void)n_in; (void)out_size; (void)ws_size;
  const float* input = (const float*)d_in[0];
  const float* h0    = (const float*)d_in[1];
  const float* p     = (const float*)d_in[2];
  const float* W_ih  = (const float*)d_in[3];
  const float* b_ih  = (const float*)d_in[4];
  const float* W_hh  = (const float*)d_in[5];
  const float* b_hh  = (const float*)d_in[6];
  const float* bias  = (const float*)d_in[7];
  float* out = (float*)d_out;

  char* ws = (char*)d_ws;
  f16* WhhE = (f16*)ws;                  // 64*512*512*2 = 33,554,432 B
  f16* WihE = (f16*)(ws + 33554432);     // 64*512*256*2 = 16,777,216 B
  float* be = (float*)(ws + 50331648);   // 64*512*4     =    131,072 B

  mix_whh_kernel<<<512, 512, 0, stream>>>(W_hh, p, WhhE);
  mix_wih_kernel<<<512, 256, 0, stream>>>(W_ih, p, WihE);
  beff_kernel<<<64, 512, 0, stream>>>(p, b_ih, b_hh, bias, be);
  xgemm_kernel<<<dim3(8, 8, 64), 256, 0, stream>>>(input, WihE, be, out);
  chunk_kernel<<<64, 512, 0, stream>>>(WhhE, h0, out);
}